// Round 11
// baseline (566.585 us; speedup 1.0000x reference)
//
#include <hip/hip_runtime.h>

#define NMAT 2048
#define KATTR 64
#define CAP 128
#define NITER 10
#define NSTRIPE 128    // bf16 stripes of 16 cols: blocked M layout [s][row][16]
#define NSTRIPEF 256   // fp32 stripes of 8 cols:  blocked Mf layout [s][row][8]
#define LSTRIDE 9      // dwords per row in k1s LDS (9 coprime 32 -> bank spread)

typedef unsigned short ushort4v __attribute__((ext_vector_type(4)));

__device__ __forceinline__ unsigned short f2bf(float f) {
  unsigned u = __float_as_uint(f);
  return (unsigned short)((u + 0x7fff + ((u >> 16) & 1)) >> 16);
}
__device__ __forceinline__ float bf2f(unsigned short b) {
  return __uint_as_float((unsigned)b << 16);
}
__device__ __forceinline__ float bflo(unsigned v) {
  return __uint_as_float(v << 16);
}
__device__ __forceinline__ float bfhi(unsigned v) {
  return __uint_as_float(v & 0xffff0000u);
}
// swizzled LDS dword index for 4-row interleaved T1 tile (proven R4-R10)
__device__ __forceinline__ int swz(int c) { return 4 * c + (((c >> 3) & 7) << 2); }
// blocked bf16 M element offset (row i, col j)
__device__ __forceinline__ size_t bidx(int i, int j) {
  return ((size_t)(j >> 4) * NMAT + i) * 16 + (j & 15);
}
// blocked fp32 Mf element offset (row i, col j)
__device__ __forceinline__ size_t bidx32(int i, int j) {
  return ((size_t)(j >> 3) * NMAT + i) * 8 + (j & 7);
}

// --------------------------------------------------------------------------
// Build padded adjacency (ELL) for pattern(A); B == (A!=0), symmetric.
// --------------------------------------------------------------------------
__global__ __launch_bounds__(256) void k_build(
    const float* __restrict__ A, unsigned short* __restrict__ idx,
    unsigned short* __restrict__ idxT, int* __restrict__ cnt) {
  __shared__ int lcnt;
  int r = blockIdx.x;
  if (threadIdx.x == 0) lcnt = 0;
  __syncthreads();
  const float* row = A + (size_t)r * NMAT;
  for (int c = threadIdx.x; c < NMAT; c += 256) {
    if (row[c] != 0.0f) {
      int p = atomicAdd(&lcnt, 1);
      if (p < CAP) {
        idx[r * CAP + p] = (unsigned short)c;
        if (idxT) idxT[(size_t)p * NMAT + r] = (unsigned short)c;
      }
    }
  }
  __syncthreads();
  if (threadIdx.x == 0) cnt[r] = lcnt < CAP ? lcnt : CAP;
}

// --------------------------------------------------------------------------
// Counting sort of node ids by degree -> perm (waves then see uniform trip
// counts: kills the ~1.7x ragged-loop divergence in the gather kernels).
// --------------------------------------------------------------------------
__global__ __launch_bounds__(1024) void k_sort(const int* __restrict__ cnt,
                                               unsigned short* __restrict__ perm) {
  __shared__ int hist[CAP + 1];
  __shared__ int base[CAP + 1];
  int tid = threadIdx.x;
  if (tid <= CAP) hist[tid] = 0;
  __syncthreads();
  for (int r = tid; r < NMAT; r += 1024) atomicAdd(&hist[cnt[r]], 1);
  __syncthreads();
  if (tid == 0) {
    int acc = 0;
    for (int b = 0; b <= CAP; ++b) {
      base[b] = acc;
      acc += hist[b];
      hist[b] = 0;
    }
  }
  __syncthreads();
  for (int r = tid; r < NMAT; r += 1024) {
    int b = cnt[r];
    int pos = base[b] + atomicAdd(&hist[b], 1);
    perm[pos] = (unsigned short)r;
  }
}

__global__ __launch_bounds__(256) void k_norm(const float* __restrict__ Nin,
                                              float* __restrict__ Nout) {
  int row = blockIdx.x * 4 + (threadIdx.x >> 6);
  int lane = threadIdx.x & 63;
  float v = Nin[(size_t)row * KATTR + lane];
  float ss = v * v;
#pragma unroll
  for (int o = 32; o > 0; o >>= 1) ss += __shfl_xor(ss, o);
  float nrm = sqrtf(ss);
  Nout[(size_t)row * KATTR + lane] = (nrm > 0.f) ? v / nrm : 0.f;
}

__global__ void k_gatherN(const unsigned short* __restrict__ idx,
                          const int* __restrict__ cnt,
                          const float* __restrict__ Nn,
                          float* __restrict__ C) {
  int i = blockIdx.x;
  int lane = threadIdx.x;  // blockDim = 64
  int nn = cnt[i];
  const unsigned short* ip = idx + i * CAP;
  float acc = 0.f;
  for (int t = 0; t < nn; ++t) {
    int k = ip[t];
    acc += Nn[(size_t)k * KATTR + lane];
  }
  C[(size_t)i * KATTR + lane] = acc;
}

__global__ __launch_bounds__(256) void k_transpose(const float* __restrict__ H,
                                                   float* __restrict__ Ht) {
  __shared__ float tile[64][65];
  int j0 = blockIdx.x * 64;
  int i0 = blockIdx.y * 64;
  int c = threadIdx.x & 63;
  int r0 = threadIdx.x >> 6;
  for (int r = r0; r < 64; r += 4)
    tile[r][c] = H[(size_t)(j0 + r) * NMAT + i0 + c];
  __syncthreads();
  for (int r = r0; r < 64; r += 4)
    Ht[(size_t)(i0 + r) * NMAT + j0 + c] = tile[c][r];
}

// --------------------------------------------------------------------------
// q = Nm>0&dm>0 ? Nm*rsqrt(Nm*dm) : 0.
// M0 (bf16 blocked, iter-0 gather input), Q2 = alpha*q^2 (row-major),
// M0base = bf16((1-a)*q*Ht) (row-major), q row-major (final epilogue).
// --------------------------------------------------------------------------
__global__ __launch_bounds__(256) void k_q(
    const float* __restrict__ N1n, const float* __restrict__ C1,
    const float* __restrict__ N2n, const float* __restrict__ C2,
    const float* __restrict__ Ht, float* __restrict__ q,
    float* __restrict__ Q2, unsigned short* __restrict__ Mblk,
    unsigned short* __restrict__ M0base) {
  __shared__ float sA[64][68];
  __shared__ float sB[64][68];
  int i0 = blockIdx.y * 64, j0 = blockIdx.x * 64;
  int c = threadIdx.x & 63, r0 = threadIdx.x >> 6;
  int tx = threadIdx.x & 15, ty = threadIdx.x >> 4;
  const float alpha = 0.82f;

  float nmv[4][4] = {};
  float dmv[4][4] = {};

  for (int r = r0; r < 64; r += 4) {
    sA[c][r] = N1n[(size_t)(i0 + r) * KATTR + c];
    sB[c][r] = N2n[(size_t)(j0 + r) * KATTR + c];
  }
  __syncthreads();
#pragma unroll 4
  for (int k = 0; k < 64; ++k) {
    float4 a = *(const float4*)&sA[k][ty * 4];
    float4 b = *(const float4*)&sB[k][tx * 4];
    float av[4] = {a.x, a.y, a.z, a.w};
    float bv[4] = {b.x, b.y, b.z, b.w};
#pragma unroll
    for (int ii = 0; ii < 4; ++ii)
#pragma unroll
      for (int jj = 0; jj < 4; ++jj)
        nmv[ii][jj] = fmaf(av[ii], bv[jj], nmv[ii][jj]);
  }
  __syncthreads();
  for (int r = r0; r < 64; r += 4) {
    sA[c][r] = C1[(size_t)(i0 + r) * KATTR + c];
    sB[c][r] = C2[(size_t)(j0 + r) * KATTR + c];
  }
  __syncthreads();
#pragma unroll 4
  for (int k = 0; k < 64; ++k) {
    float4 a = *(const float4*)&sA[k][ty * 4];
    float4 b = *(const float4*)&sB[k][tx * 4];
    float av[4] = {a.x, a.y, a.z, a.w};
    float bv[4] = {b.x, b.y, b.z, b.w};
#pragma unroll
    for (int ii = 0; ii < 4; ++ii)
#pragma unroll
      for (int jj = 0; jj < 4; ++jj)
        dmv[ii][jj] = fmaf(av[ii], bv[jj], dmv[ii][jj]);
  }

#pragma unroll
  for (int ii = 0; ii < 4; ++ii) {
    int i = i0 + ty * 4 + ii;
    int jb = j0 + tx * 4;
    size_t base = (size_t)i * NMAT + jb;
    float4 hv = *(const float4*)&Ht[base];
    float hvv[4] = {hv.x, hv.y, hv.z, hv.w};
    float qv[4], q2v[4];
    ushort4v mv, m0v;
#pragma unroll
    for (int jj = 0; jj < 4; ++jj) {
      float nmx = nmv[ii][jj];
      float D = nmx * dmv[ii][jj];
      float qq = (D > 0.f) ? nmx * rsqrtf(D) : 0.f;
      qv[jj] = qq;
      q2v[jj] = alpha * qq * qq;
      float m0 = qq * hvv[jj];
      mv[jj] = f2bf(m0);
      m0v[jj] = f2bf((1.0f - alpha) * m0);
    }
    *(float4*)&q[base] = make_float4(qv[0], qv[1], qv[2], qv[3]);
    *(float4*)&Q2[base] = make_float4(q2v[0], q2v[1], q2v[2], q2v[3]);
    *(ushort4v*)&Mblk[bidx(i, jb)] = mv;
    *(ushort4v*)&M0base[base] = m0v;
  }
}

// --------------------------------------------------------------------------
// k1s: T1 = B1 @ M, streamed stripe in LDS + degree-sorted row scheduling.
// Wave = 32 similar-degree rows (perm1) -> max(nn) ~ mean(nn), removing the
// ~1.7x ragged-loop inflation diagnosed from R10's plateau.
// --------------------------------------------------------------------------
__global__ __launch_bounds__(1024, 8) void k1s(
    const unsigned short* __restrict__ idx1, const int* __restrict__ cnt1,
    const unsigned short* __restrict__ perm1,
    const unsigned short* __restrict__ Mblk, float* __restrict__ T1) {
  __shared__ unsigned lds[NMAT * LSTRIDE];  // 73,728 B -> 2 blocks/CU
  int stripe = blockIdx.x & (NSTRIPE - 1);
  int chunk = blockIdx.x >> 7;  // 0..3
  int tid = threadIdx.x;
  const unsigned* src = (const unsigned*)(Mblk + (size_t)stripe * NMAT * 16);
#pragma unroll
  for (int p = 0; p < 4; ++p) {
    int e = p * 4096 + tid * 4;
    uint4 v = *(const uint4*)(src + e);
    int row = e >> 3;
    int cc = e & 7;
    lds[row * LSTRIDE + cc] = v.x;
    lds[row * LSTRIDE + cc + 1] = v.y;
    lds[row * LSTRIDE + cc + 2] = v.z;
    lds[row * LSTRIDE + cc + 3] = v.w;
  }
  __syncthreads();

  int i = perm1[chunk * 512 + (tid >> 1)];
  int h = tid & 1;
  int nn = cnt1[i];
  const unsigned short* ip = idx1 + i * CAP;
  float a0 = 0, a1 = 0, a2 = 0, a3 = 0, a4 = 0, a5 = 0, a6 = 0, a7 = 0;
  int t = 0;
  for (; t + 2 <= nn; t += 2) {
    unsigned pr = *(const unsigned*)(ip + t);
    int ka = (int)(pr & 0xffff) * LSTRIDE + h * 4;
    int kb = (int)(pr >> 16) * LSTRIDE + h * 4;
    unsigned w0 = lds[ka], w1 = lds[ka + 1], w2 = lds[ka + 2], w3 = lds[ka + 3];
    unsigned x0 = lds[kb], x1 = lds[kb + 1], x2 = lds[kb + 2], x3 = lds[kb + 3];
    a0 += bflo(w0) + bflo(x0); a1 += bfhi(w0) + bfhi(x0);
    a2 += bflo(w1) + bflo(x1); a3 += bfhi(w1) + bfhi(x1);
    a4 += bflo(w2) + bflo(x2); a5 += bfhi(w2) + bfhi(x2);
    a6 += bflo(w3) + bflo(x3); a7 += bfhi(w3) + bfhi(x3);
  }
  if (t < nn) {
    int ka = (int)ip[t] * LSTRIDE + h * 4;
    unsigned w0 = lds[ka], w1 = lds[ka + 1], w2 = lds[ka + 2], w3 = lds[ka + 3];
    a0 += bflo(w0); a1 += bfhi(w0);
    a2 += bflo(w1); a3 += bfhi(w1);
    a4 += bflo(w2); a5 += bfhi(w2);
    a6 += bflo(w3); a7 += bfhi(w3);
  }
  float* dst = T1 + (size_t)i * NMAT + stripe * 16 + h * 8;
  *(float4*)dst = make_float4(a0, a1, a2, a3);
  *(float4*)(dst + 4) = make_float4(a4, a5, a6, a7);
}

// --------------------------------------------------------------------------
// k1sf: fp32 variant (final iteration). Mf blocked [s][row][8], stripe=8 cols.
// --------------------------------------------------------------------------
__global__ __launch_bounds__(1024, 8) void k1sf(
    const unsigned short* __restrict__ idx1, const int* __restrict__ cnt1,
    const unsigned short* __restrict__ perm1, const float* __restrict__ Mfb,
    float* __restrict__ T1) {
  __shared__ unsigned lds[NMAT * LSTRIDE];
  int stripe = blockIdx.x & (NSTRIPEF - 1);
  int chunk = blockIdx.x >> 8;  // 0..3
  int tid = threadIdx.x;
  const unsigned* src = (const unsigned*)(Mfb + (size_t)stripe * NMAT * 8);
#pragma unroll
  for (int p = 0; p < 4; ++p) {
    int e = p * 4096 + tid * 4;
    uint4 v = *(const uint4*)(src + e);
    int row = e >> 3;
    int cc = e & 7;
    lds[row * LSTRIDE + cc] = v.x;
    lds[row * LSTRIDE + cc + 1] = v.y;
    lds[row * LSTRIDE + cc + 2] = v.z;
    lds[row * LSTRIDE + cc + 3] = v.w;
  }
  __syncthreads();

  int i = perm1[chunk * 512 + (tid >> 1)];
  int h = tid & 1;  // dwords h*4..h*4+3 = 4 fp32 cols
  int nn = cnt1[i];
  const unsigned short* ip = idx1 + i * CAP;
  float a0 = 0, a1 = 0, a2 = 0, a3 = 0;
  float b0 = 0, b1 = 0, b2 = 0, b3 = 0;
  int t = 0;
  for (; t + 2 <= nn; t += 2) {
    unsigned pr = *(const unsigned*)(ip + t);
    int ka = (int)(pr & 0xffff) * LSTRIDE + h * 4;
    int kb = (int)(pr >> 16) * LSTRIDE + h * 4;
    a0 += __uint_as_float(lds[ka]);     a1 += __uint_as_float(lds[ka + 1]);
    a2 += __uint_as_float(lds[ka + 2]); a3 += __uint_as_float(lds[ka + 3]);
    b0 += __uint_as_float(lds[kb]);     b1 += __uint_as_float(lds[kb + 1]);
    b2 += __uint_as_float(lds[kb + 2]); b3 += __uint_as_float(lds[kb + 3]);
  }
  if (t < nn) {
    int ka = (int)ip[t] * LSTRIDE + h * 4;
    a0 += __uint_as_float(lds[ka]);     a1 += __uint_as_float(lds[ka + 1]);
    a2 += __uint_as_float(lds[ka + 2]); a3 += __uint_as_float(lds[ka + 3]);
  }
  float* dst = T1 + (size_t)i * NMAT + stripe * 8 + h * 4;
  *(float4*)dst = make_float4(a0 + b0, a1 + b1, a2 + b2, a3 + b3);
}

// --------------------------------------------------------------------------
// k2s: S = T1 @ B2^T with degree-sorted j scheduling. Phase B gathers j in
// perm2 order (uniform wave trip counts), parks S in an LDS buffer indexed
// by true j; uniform pass then does coalesced epilogue reads/writes.
// Iters 0-7 -> blocked bf16 M; iter 8 -> blocked fp32 Mf.
// --------------------------------------------------------------------------
__global__ __launch_bounds__(1024, 8) void k2s(
    const unsigned short* __restrict__ idx2T, const int* __restrict__ cnt2,
    const unsigned short* __restrict__ perm2, const float* __restrict__ T1,
    const float* __restrict__ Q2, const unsigned short* __restrict__ M0base,
    unsigned short* __restrict__ Moutb, float* __restrict__ MoutF,
    int out32) {
  __shared__ float lds[4 * NMAT + 32];
  __shared__ float sS[4 * NMAT];
  int i0 = blockIdx.x * 4;
  int tid = threadIdx.x;
  int c0 = tid * 2;
  float2 v[4];
#pragma unroll
  for (int r = 0; r < 4; ++r)
    v[r] = *(const float2*)(T1 + (size_t)(i0 + r) * NMAT + c0);
  *(float4*)&lds[swz(c0)] = make_float4(v[0].x, v[1].x, v[2].x, v[3].x);
  *(float4*)&lds[swz(c0 + 1)] = make_float4(v[0].y, v[1].y, v[2].y, v[3].y);
  __syncthreads();

#pragma unroll
  for (int jj = 0; jj < 2; ++jj) {
    int j = perm2[jj * 1024 + tid];
    int nn = cnt2[j];
    const unsigned short* ip = idx2T + j;
    float s0 = 0.f, s1 = 0.f, s2 = 0.f, s3 = 0.f;
    float u0 = 0.f, u1 = 0.f, u2 = 0.f, u3 = 0.f;
    int t = 0;
    for (; t + 4 <= nn; t += 4) {
      int ka = ip[(size_t)t * NMAT];
      int kb = ip[(size_t)(t + 1) * NMAT];
      int kc = ip[(size_t)(t + 2) * NMAT];
      int kd = ip[(size_t)(t + 3) * NMAT];
      float4 va = *(const float4*)&lds[swz(ka)];
      float4 vb = *(const float4*)&lds[swz(kb)];
      float4 vc = *(const float4*)&lds[swz(kc)];
      float4 vd = *(const float4*)&lds[swz(kd)];
      s0 += va.x + vc.x; s1 += va.y + vc.y;
      s2 += va.z + vc.z; s3 += va.w + vc.w;
      u0 += vb.x + vd.x; u1 += vb.y + vd.y;
      u2 += vb.z + vd.z; u3 += vb.w + vd.w;
    }
    for (; t < nn; ++t) {
      int ka = ip[(size_t)t * NMAT];
      float4 va = *(const float4*)&lds[swz(ka)];
      s0 += va.x; s1 += va.y; s2 += va.z; s3 += va.w;
    }
    sS[j] = s0 + u0;
    sS[NMAT + j] = s1 + u1;
    sS[2 * NMAT + j] = s2 + u2;
    sS[3 * NMAT + j] = s3 + u3;
  }
  __syncthreads();

#pragma unroll
  for (int jj = 0; jj < 2; ++jj) {
    int j = jj * 1024 + tid;
    float sa[4] = {sS[j], sS[NMAT + j], sS[2 * NMAT + j], sS[3 * NMAT + j]};
    if (out32) {
#pragma unroll
      for (int r = 0; r < 4; ++r) {
        size_t off = (size_t)(i0 + r) * NMAT + j;
        MoutF[bidx32(i0 + r, j)] = fmaf(Q2[off], sa[r], bf2f(M0base[off]));
      }
    } else {
#pragma unroll
      for (int r = 0; r < 4; ++r) {
        size_t off = (size_t)(i0 + r) * NMAT + j;
        Moutb[bidx(i0 + r, j)] = f2bf(fmaf(Q2[off], sa[r], bf2f(M0base[off])));
      }
    }
  }
}

// --------------------------------------------------------------------------
// k2fin: final-iteration phase B. Same sorted gather; epilogue
// s_out = (1-a)*Ht + a*q*S (coalesced q/Ht reads, row-major s_out write).
// --------------------------------------------------------------------------
__global__ __launch_bounds__(1024, 8) void k2fin(
    const unsigned short* __restrict__ idx2T, const int* __restrict__ cnt2,
    const unsigned short* __restrict__ perm2, const float* __restrict__ T1,
    const float* __restrict__ q, const float* __restrict__ Ht,
    float* __restrict__ sout) {
  __shared__ float lds[4 * NMAT + 32];
  __shared__ float sS[4 * NMAT];
  int i0 = blockIdx.x * 4;
  int tid = threadIdx.x;
  int c0 = tid * 2;
  float2 v[4];
#pragma unroll
  for (int r = 0; r < 4; ++r)
    v[r] = *(const float2*)(T1 + (size_t)(i0 + r) * NMAT + c0);
  *(float4*)&lds[swz(c0)] = make_float4(v[0].x, v[1].x, v[2].x, v[3].x);
  *(float4*)&lds[swz(c0 + 1)] = make_float4(v[0].y, v[1].y, v[2].y, v[3].y);
  __syncthreads();

#pragma unroll
  for (int jj = 0; jj < 2; ++jj) {
    int j = perm2[jj * 1024 + tid];
    int nn = cnt2[j];
    const unsigned short* ip = idx2T + j;
    float s0 = 0.f, s1 = 0.f, s2 = 0.f, s3 = 0.f;
    float u0 = 0.f, u1 = 0.f, u2 = 0.f, u3 = 0.f;
    int t = 0;
    for (; t + 4 <= nn; t += 4) {
      int ka = ip[(size_t)t * NMAT];
      int kb = ip[(size_t)(t + 1) * NMAT];
      int kc = ip[(size_t)(t + 2) * NMAT];
      int kd = ip[(size_t)(t + 3) * NMAT];
      float4 va = *(const float4*)&lds[swz(ka)];
      float4 vb = *(const float4*)&lds[swz(kb)];
      float4 vc = *(const float4*)&lds[swz(kc)];
      float4 vd = *(const float4*)&lds[swz(kd)];
      s0 += va.x + vc.x; s1 += va.y + vc.y;
      s2 += va.z + vc.z; s3 += va.w + vc.w;
      u0 += vb.x + vd.x; u1 += vb.y + vd.y;
      u2 += vb.z + vd.z; u3 += vb.w + vd.w;
    }
    for (; t < nn; ++t) {
      int ka = ip[(size_t)t * NMAT];
      float4 va = *(const float4*)&lds[swz(ka)];
      s0 += va.x; s1 += va.y; s2 += va.z; s3 += va.w;
    }
    sS[j] = s0 + u0;
    sS[NMAT + j] = s1 + u1;
    sS[2 * NMAT + j] = s2 + u2;
    sS[3 * NMAT + j] = s3 + u3;
  }
  __syncthreads();

  const float alpha = 0.82f;
  const float oma = 1.0f - alpha;
#pragma unroll
  for (int jj = 0; jj < 2; ++jj) {
    int j = jj * 1024 + tid;
    float sa[4] = {sS[j], sS[NMAT + j], sS[2 * NMAT + j], sS[3 * NMAT + j]};
#pragma unroll
    for (int r = 0; r < 4; ++r) {
      size_t off = (size_t)(i0 + r) * NMAT + j;
      sout[off] = oma * Ht[off] + alpha * q[off] * sa[r];
    }
  }
}

extern "C" void kernel_launch(void* const* d_in, const int* in_sizes, int n_in,
                              void* d_out, int out_size, void* d_ws,
                              size_t ws_size, hipStream_t stream) {
  const float* A1 = (const float*)d_in[0];
  const float* A2 = (const float*)d_in[1];
  const float* N1 = (const float*)d_in[2];
  const float* N2 = (const float*)d_in[3];
  const float* H = (const float*)d_in[4];
  float* s_out = (float*)d_out;

  char* p = (char*)d_ws;
  auto take = [&](size_t bytes) {
    char* r = p;
    p += (bytes + 255) & ~(size_t)255;
    return r;
  };
  unsigned short* idx1 = (unsigned short*)take((size_t)NMAT * CAP * 2);
  unsigned short* idx2 = (unsigned short*)take((size_t)NMAT * CAP * 2);
  unsigned short* idx2T = (unsigned short*)take((size_t)CAP * NMAT * 2);
  int* cnt1 = (int*)take((size_t)NMAT * 4);
  int* cnt2 = (int*)take((size_t)NMAT * 4);
  unsigned short* perm1 = (unsigned short*)take((size_t)NMAT * 2);
  unsigned short* perm2 = (unsigned short*)take((size_t)NMAT * 2);
  float* N1n = (float*)take((size_t)NMAT * KATTR * 4);
  float* N2n = (float*)take((size_t)NMAT * KATTR * 4);
  float* C1 = (float*)take((size_t)NMAT * KATTR * 4);
  float* C2 = (float*)take((size_t)NMAT * KATTR * 4);
  float* Ht = (float*)take((size_t)NMAT * NMAT * 4);
  float* q = (float*)take((size_t)NMAT * NMAT * 4);
  float* Q2 = (float*)take((size_t)NMAT * NMAT * 4);
  unsigned short* Mb0 = (unsigned short*)take((size_t)NMAT * NMAT * 2);
  unsigned short* Mb1 = (unsigned short*)take((size_t)NMAT * NMAT * 2);
  unsigned short* M0b = (unsigned short*)take((size_t)NMAT * NMAT * 2);
  float* Mf = (float*)take((size_t)NMAT * NMAT * 4);
  float* T1 = (float*)take((size_t)NMAT * NMAT * 4);
  if ((size_t)(p - (char*)d_ws) > ws_size) return;

  k_build<<<NMAT, 256, 0, stream>>>(A1, idx1, (unsigned short*)nullptr, cnt1);
  k_build<<<NMAT, 256, 0, stream>>>(A2, idx2, idx2T, cnt2);
  k_sort<<<1, 1024, 0, stream>>>(cnt1, perm1);
  k_sort<<<1, 1024, 0, stream>>>(cnt2, perm2);
  k_norm<<<NMAT / 4, 256, 0, stream>>>(N1, N1n);
  k_norm<<<NMAT / 4, 256, 0, stream>>>(N2, N2n);
  k_gatherN<<<NMAT, 64, 0, stream>>>(idx1, cnt1, N1n, C1);
  k_gatherN<<<NMAT, 64, 0, stream>>>(idx2, cnt2, N2n, C2);
  k_transpose<<<dim3(32, 32), 256, 0, stream>>>(H, Ht);
  k_q<<<dim3(32, 32), 256, 0, stream>>>(N1n, C1, N2n, C2, Ht, q, Q2, Mb0,
                                        M0b);
  for (int it = 0; it < NITER - 1; ++it) {
    const unsigned short* Min = (it & 1) ? Mb1 : Mb0;
    unsigned short* Mout = (it & 1) ? Mb0 : Mb1;
    int out32 = (it == NITER - 2) ? 1 : 0;
    k1s<<<4 * NSTRIPE, 1024, 0, stream>>>(idx1, cnt1, perm1, Min, T1);
    k2s<<<NMAT / 4, 1024, 0, stream>>>(idx2T, cnt2, perm2, T1, Q2, M0b, Mout,
                                       Mf, out32);
  }
  k1sf<<<4 * NSTRIPEF, 1024, 0, stream>>>(idx1, cnt1, perm1, Mf, T1);
  k2fin<<<NMAT / 4, 1024, 0, stream>>>(idx2T, cnt2, perm2, T1, q, Ht, s_out);
}

// Round 12
// 465.015 us; speedup vs baseline: 1.2184x; 1.2184x over previous
//
#include <hip/hip_runtime.h>

#define NMAT 2048
#define KATTR 64
#define CAP 128
#define NITER 10
#define NSTRIPE 128   // bf16 stripes of 16 cols: blocked M layout [s][row][16]

typedef unsigned short ushort4v __attribute__((ext_vector_type(4)));

__device__ __forceinline__ unsigned short f2bf(float f) {
  unsigned u = __float_as_uint(f);
  return (unsigned short)((u + 0x7fff + ((u >> 16) & 1)) >> 16);
}
__device__ __forceinline__ float bf2f(unsigned short b) {
  return __uint_as_float((unsigned)b << 16);
}
// bf16 pair in one uint (little-endian: low half = even col)
__device__ __forceinline__ float bflo(unsigned v) {
  return __uint_as_float(v << 16);
}
__device__ __forceinline__ float bfhi(unsigned v) {
  return __uint_as_float(v & 0xffff0000u);
}
// swizzled LDS dword index for 4-row interleaved T1 tile (proven R4-R10)
__device__ __forceinline__ int swz(int c) { return 4 * c + (((c >> 3) & 7) << 2); }
// blocked bf16 M element offset (row i, col j)
__device__ __forceinline__ size_t bidx(int i, int j) {
  return ((size_t)(j >> 4) * NMAT + i) * 16 + (j & 15);
}

// --------------------------------------------------------------------------
// Build padded adjacency (ELL) for pattern(A); B == (A!=0), symmetric.
// --------------------------------------------------------------------------
__global__ __launch_bounds__(256) void k_build(
    const float* __restrict__ A, unsigned short* __restrict__ idx,
    unsigned short* __restrict__ idxT, int* __restrict__ cnt) {
  __shared__ int lcnt;
  int r = blockIdx.x;
  if (threadIdx.x == 0) lcnt = 0;
  __syncthreads();
  const float* row = A + (size_t)r * NMAT;
  for (int c = threadIdx.x; c < NMAT; c += 256) {
    if (row[c] != 0.0f) {
      int p = atomicAdd(&lcnt, 1);
      if (p < CAP) {
        idx[r * CAP + p] = (unsigned short)c;
        if (idxT) idxT[(size_t)p * NMAT + r] = (unsigned short)c;
      }
    }
  }
  __syncthreads();
  if (threadIdx.x == 0) cnt[r] = lcnt < CAP ? lcnt : CAP;
}

__global__ __launch_bounds__(256) void k_norm(const float* __restrict__ Nin,
                                              float* __restrict__ Nout) {
  int row = blockIdx.x * 4 + (threadIdx.x >> 6);
  int lane = threadIdx.x & 63;
  float v = Nin[(size_t)row * KATTR + lane];
  float ss = v * v;
#pragma unroll
  for (int o = 32; o > 0; o >>= 1) ss += __shfl_xor(ss, o);
  float nrm = sqrtf(ss);
  Nout[(size_t)row * KATTR + lane] = (nrm > 0.f) ? v / nrm : 0.f;
}

__global__ void k_gatherN(const unsigned short* __restrict__ idx,
                          const int* __restrict__ cnt,
                          const float* __restrict__ Nn,
                          float* __restrict__ C) {
  int i = blockIdx.x;
  int lane = threadIdx.x;  // blockDim = 64
  int nn = cnt[i];
  const unsigned short* ip = idx + i * CAP;
  float acc = 0.f;
  for (int t = 0; t < nn; ++t) {
    int k = ip[t];
    acc += Nn[(size_t)k * KATTR + lane];
  }
  C[(size_t)i * KATTR + lane] = acc;
}

__global__ __launch_bounds__(256) void k_transpose(const float* __restrict__ H,
                                                   float* __restrict__ Ht) {
  __shared__ float tile[64][65];
  int j0 = blockIdx.x * 64;
  int i0 = blockIdx.y * 64;
  int c = threadIdx.x & 63;
  int r0 = threadIdx.x >> 6;
  for (int r = r0; r < 64; r += 4)
    tile[r][c] = H[(size_t)(j0 + r) * NMAT + i0 + c];
  __syncthreads();
  for (int r = r0; r < 64; r += 4)
    Ht[(size_t)(i0 + r) * NMAT + j0 + c] = tile[c][r];
}

// --------------------------------------------------------------------------
// q = Nm>0&dm>0 ? Nm*rsqrt(Nm*dm) : 0.
// M0 (bf16 blocked, iter-0 gather input), Q2 = alpha*q^2 (row-major),
// M0base = bf16((1-a)*q*Ht) (row-major), q row-major (final epilogue).
// --------------------------------------------------------------------------
__global__ __launch_bounds__(256) void k_q(
    const float* __restrict__ N1n, const float* __restrict__ C1,
    const float* __restrict__ N2n, const float* __restrict__ C2,
    const float* __restrict__ Ht, float* __restrict__ q,
    float* __restrict__ Q2, unsigned short* __restrict__ Mblk,
    unsigned short* __restrict__ M0base) {
  __shared__ float sA[64][68];
  __shared__ float sB[64][68];
  int i0 = blockIdx.y * 64, j0 = blockIdx.x * 64;
  int c = threadIdx.x & 63, r0 = threadIdx.x >> 6;
  int tx = threadIdx.x & 15, ty = threadIdx.x >> 4;
  const float alpha = 0.82f;

  float nmv[4][4] = {};
  float dmv[4][4] = {};

  for (int r = r0; r < 64; r += 4) {
    sA[c][r] = N1n[(size_t)(i0 + r) * KATTR + c];
    sB[c][r] = N2n[(size_t)(j0 + r) * KATTR + c];
  }
  __syncthreads();
#pragma unroll 4
  for (int k = 0; k < 64; ++k) {
    float4 a = *(const float4*)&sA[k][ty * 4];
    float4 b = *(const float4*)&sB[k][tx * 4];
    float av[4] = {a.x, a.y, a.z, a.w};
    float bv[4] = {b.x, b.y, b.z, b.w};
#pragma unroll
    for (int ii = 0; ii < 4; ++ii)
#pragma unroll
      for (int jj = 0; jj < 4; ++jj)
        nmv[ii][jj] = fmaf(av[ii], bv[jj], nmv[ii][jj]);
  }
  __syncthreads();
  for (int r = r0; r < 64; r += 4) {
    sA[c][r] = C1[(size_t)(i0 + r) * KATTR + c];
    sB[c][r] = C2[(size_t)(j0 + r) * KATTR + c];
  }
  __syncthreads();
#pragma unroll 4
  for (int k = 0; k < 64; ++k) {
    float4 a = *(const float4*)&sA[k][ty * 4];
    float4 b = *(const float4*)&sB[k][tx * 4];
    float av[4] = {a.x, a.y, a.z, a.w};
    float bv[4] = {b.x, b.y, b.z, b.w};
#pragma unroll
    for (int ii = 0; ii < 4; ++ii)
#pragma unroll
      for (int jj = 0; jj < 4; ++jj)
        dmv[ii][jj] = fmaf(av[ii], bv[jj], dmv[ii][jj]);
  }

#pragma unroll
  for (int ii = 0; ii < 4; ++ii) {
    int i = i0 + ty * 4 + ii;
    int jb = j0 + tx * 4;
    size_t base = (size_t)i * NMAT + jb;
    float4 hv = *(const float4*)&Ht[base];
    float hvv[4] = {hv.x, hv.y, hv.z, hv.w};
    float qv[4], q2v[4];
    ushort4v mv, m0v;
#pragma unroll
    for (int jj = 0; jj < 4; ++jj) {
      float nmx = nmv[ii][jj];
      float D = nmx * dmv[ii][jj];
      float qq = (D > 0.f) ? nmx * rsqrtf(D) : 0.f;
      qv[jj] = qq;
      q2v[jj] = alpha * qq * qq;
      float m0 = qq * hvv[jj];
      mv[jj] = f2bf(m0);
      m0v[jj] = f2bf((1.0f - alpha) * m0);
    }
    *(float4*)&q[base] = make_float4(qv[0], qv[1], qv[2], qv[3]);
    *(float4*)&Q2[base] = make_float4(q2v[0], q2v[1], q2v[2], q2v[3]);
    *(ushort4v*)&Mblk[bidx(i, jb)] = mv;
    *(ushort4v*)&M0base[base] = m0v;
  }
}

// --------------------------------------------------------------------------
// k1s: T1 = B1 @ M, streamed stripe in LDS. LSTRIDE=8 (vs R10's 9): the
// stripe is now an identity copy (uint4 staging, conflict-free) and each
// thread's 16B row-slice is 16B-aligned -> ONE ds_read_b128 per edge
// (R10 paid 4 scalar ds_read_b32 + conflicts -> its 25 us). Arithmetic and
// summation order bit-identical to R10.
// --------------------------------------------------------------------------
__global__ __launch_bounds__(1024, 8) void k1s(
    const unsigned short* __restrict__ idx1, const int* __restrict__ cnt1,
    const unsigned short* __restrict__ Mblk, float* __restrict__ T1) {
  __shared__ __align__(16) unsigned lds[NMAT * 8];  // 64 KB -> 2 blocks/CU
  int stripe = blockIdx.x & (NSTRIPE - 1);
  int chunk = blockIdx.x >> 7;  // 0..3
  int tid = threadIdx.x;
  const unsigned* src = (const unsigned*)(Mblk + (size_t)stripe * NMAT * 16);
#pragma unroll
  for (int p = 0; p < 4; ++p) {
    int e = p * 4096 + tid * 4;  // dword index == LDS dword index (identity)
    *(uint4*)&lds[e] = *(const uint4*)(src + e);
  }
  __syncthreads();

  int i = chunk * 512 + (tid >> 1);
  int h = tid & 1;  // dwords h*4..h*4+3 = cols h*8..h*8+7 of the stripe
  int nn = cnt1[i];
  const unsigned short* ip = idx1 + i * CAP;
  float a0 = 0, a1 = 0, a2 = 0, a3 = 0, a4 = 0, a5 = 0, a6 = 0, a7 = 0;
  int hh = h * 4;
  int t = 0;
  for (; t + 2 <= nn; t += 2) {
    unsigned pr = *(const unsigned*)(ip + t);
    uint4 w = *(const uint4*)&lds[(int)(pr & 0xffff) * 8 + hh];
    uint4 x = *(const uint4*)&lds[(int)(pr >> 16) * 8 + hh];
    a0 += bflo(w.x) + bflo(x.x); a1 += bfhi(w.x) + bfhi(x.x);
    a2 += bflo(w.y) + bflo(x.y); a3 += bfhi(w.y) + bfhi(x.y);
    a4 += bflo(w.z) + bflo(x.z); a5 += bfhi(w.z) + bfhi(x.z);
    a6 += bflo(w.w) + bflo(x.w); a7 += bfhi(w.w) + bfhi(x.w);
  }
  if (t < nn) {
    uint4 w = *(const uint4*)&lds[(int)ip[t] * 8 + hh];
    a0 += bflo(w.x); a1 += bfhi(w.x);
    a2 += bflo(w.y); a3 += bfhi(w.y);
    a4 += bflo(w.z); a5 += bfhi(w.z);
    a6 += bflo(w.w); a7 += bfhi(w.w);
  }
  float* dst = T1 + (size_t)i * NMAT + stripe * 16 + h * 8;
  *(float4*)dst = make_float4(a0, a1, a2, a3);
  *(float4*)(dst + 4) = make_float4(a4, a5, a6, a7);
}

// --------------------------------------------------------------------------
// k2s: S = T1 @ B2^T (R10's proven phase B, no sort). Stages T1 rows
// i0..i0+3 into swizzled interleaved LDS; one ds_read_b128 per edge,
// 4-deep. Epilogue: M_new = fma(Q2,S,M0base) -> blocked bf16 M (iters 0-7)
// or row-major fp32 Mf (iter 8).
// --------------------------------------------------------------------------
__global__ __launch_bounds__(1024, 8) void k2s(
    const unsigned short* __restrict__ idx2T, const int* __restrict__ cnt2,
    const float* __restrict__ T1, const float* __restrict__ Q2,
    const unsigned short* __restrict__ M0base,
    unsigned short* __restrict__ Moutb, float* __restrict__ MoutF,
    int out32) {
  __shared__ float lds[4 * NMAT + 32];
  int i0 = blockIdx.x * 4;
  int tid = threadIdx.x;
  int c0 = tid * 2;
  float2 v[4];
#pragma unroll
  for (int r = 0; r < 4; ++r)
    v[r] = *(const float2*)(T1 + (size_t)(i0 + r) * NMAT + c0);
  *(float4*)&lds[swz(c0)] = make_float4(v[0].x, v[1].x, v[2].x, v[3].x);
  *(float4*)&lds[swz(c0 + 1)] = make_float4(v[0].y, v[1].y, v[2].y, v[3].y);
  __syncthreads();

#pragma unroll
  for (int jj = 0; jj < 2; ++jj) {
    int j = jj * 1024 + tid;
    int nn = cnt2[j];
    const unsigned short* ip = idx2T + j;
    float s0 = 0.f, s1 = 0.f, s2 = 0.f, s3 = 0.f;
    float u0 = 0.f, u1 = 0.f, u2 = 0.f, u3 = 0.f;
    int t = 0;
    for (; t + 4 <= nn; t += 4) {
      int ka = ip[(size_t)t * NMAT];
      int kb = ip[(size_t)(t + 1) * NMAT];
      int kc = ip[(size_t)(t + 2) * NMAT];
      int kd = ip[(size_t)(t + 3) * NMAT];
      float4 va = *(const float4*)&lds[swz(ka)];
      float4 vb = *(const float4*)&lds[swz(kb)];
      float4 vc = *(const float4*)&lds[swz(kc)];
      float4 vd = *(const float4*)&lds[swz(kd)];
      s0 += va.x + vc.x; s1 += va.y + vc.y;
      s2 += va.z + vc.z; s3 += va.w + vc.w;
      u0 += vb.x + vd.x; u1 += vb.y + vd.y;
      u2 += vb.z + vd.z; u3 += vb.w + vd.w;
    }
    for (; t < nn; ++t) {
      int ka = ip[(size_t)t * NMAT];
      float4 va = *(const float4*)&lds[swz(ka)];
      s0 += va.x; s1 += va.y; s2 += va.z; s3 += va.w;
    }
    float sa[4] = {s0 + u0, s1 + u1, s2 + u2, s3 + u3};
    if (out32) {
#pragma unroll
      for (int r = 0; r < 4; ++r) {
        size_t off = (size_t)(i0 + r) * NMAT + j;
        MoutF[off] = fmaf(Q2[off], sa[r], bf2f(M0base[off]));
      }
    } else {
#pragma unroll
      for (int r = 0; r < 4; ++r) {
        size_t off = (size_t)(i0 + r) * NMAT + j;
        Moutb[bidx(i0 + r, j)] = f2bf(fmaf(Q2[off], sa[r], bf2f(M0base[off])));
      }
    }
  }
}

// --------------------------------------------------------------------------
// Final iteration (fused, fp32 row-major gather + s_out epilogue) — the
// R9/R10 proven kernel, bit-identical numerics.
// --------------------------------------------------------------------------
__global__ __launch_bounds__(1024, 8) void k_iter(
    const unsigned short* __restrict__ idx1, const int* __restrict__ cnt1,
    const unsigned short* __restrict__ idx2T, const int* __restrict__ cnt2,
    const float* __restrict__ MinF, const float* __restrict__ q,
    const float* __restrict__ Ht, float* __restrict__ sout) {
  __shared__ float lds[4 * NMAT + 32];
  int i0 = blockIdx.x * 4;
  int tid = threadIdx.x;
  int c0 = tid * 2;

  float acc[4][2];
#pragma unroll
  for (int r = 0; r < 4; ++r) {
    int nn = cnt1[i0 + r];
    const unsigned short* ip = idx1 + (i0 + r) * CAP;
    float a0 = 0.f, a1 = 0.f;
    float b0 = 0.f, b1 = 0.f;
    int t = 0;
    for (; t + 4 <= nn; t += 4) {
      uint2 pk = *(const uint2*)(ip + t);
      int k0 = pk.x & 0xffff, k1 = pk.x >> 16;
      int k2 = pk.y & 0xffff, k3 = pk.y >> 16;
      float2 v0 = *(const float2*)(MinF + (size_t)k0 * NMAT + c0);
      float2 v1 = *(const float2*)(MinF + (size_t)k1 * NMAT + c0);
      float2 v2 = *(const float2*)(MinF + (size_t)k2 * NMAT + c0);
      float2 v3 = *(const float2*)(MinF + (size_t)k3 * NMAT + c0);
      a0 += v0.x + v1.x; a1 += v0.y + v1.y;
      b0 += v2.x + v3.x; b1 += v2.y + v3.y;
    }
    for (; t < nn; ++t) {
      float2 v0 = *(const float2*)(MinF + (size_t)ip[t] * NMAT + c0);
      a0 += v0.x; a1 += v0.y;
    }
    acc[r][0] = a0 + b0;
    acc[r][1] = a1 + b1;
  }
  *(float4*)&lds[swz(c0)] =
      make_float4(acc[0][0], acc[1][0], acc[2][0], acc[3][0]);
  *(float4*)&lds[swz(c0 + 1)] =
      make_float4(acc[0][1], acc[1][1], acc[2][1], acc[3][1]);
  __syncthreads();

  const float alpha = 0.82f;
  const float oma = 1.0f - alpha;
#pragma unroll
  for (int jj = 0; jj < 2; ++jj) {
    int j = jj * 1024 + tid;
    int nn = cnt2[j];
    const unsigned short* ip = idx2T + j;
    float s0 = 0.f, s1 = 0.f, s2 = 0.f, s3 = 0.f;
    float u0 = 0.f, u1 = 0.f, u2 = 0.f, u3 = 0.f;
    int t = 0;
    for (; t + 4 <= nn; t += 4) {
      int ka = ip[(size_t)t * NMAT];
      int kb = ip[(size_t)(t + 1) * NMAT];
      int kc = ip[(size_t)(t + 2) * NMAT];
      int kd = ip[(size_t)(t + 3) * NMAT];
      float4 va = *(const float4*)&lds[swz(ka)];
      float4 vb = *(const float4*)&lds[swz(kb)];
      float4 vc = *(const float4*)&lds[swz(kc)];
      float4 vd = *(const float4*)&lds[swz(kd)];
      s0 += va.x + vc.x; s1 += va.y + vc.y;
      s2 += va.z + vc.z; s3 += va.w + vc.w;
      u0 += vb.x + vd.x; u1 += vb.y + vd.y;
      u2 += vb.z + vd.z; u3 += vb.w + vd.w;
    }
    for (; t < nn; ++t) {
      int ka = ip[(size_t)t * NMAT];
      float4 va = *(const float4*)&lds[swz(ka)];
      s0 += va.x; s1 += va.y; s2 += va.z; s3 += va.w;
    }
    float sa[4] = {s0 + u0, s1 + u1, s2 + u2, s3 + u3};
#pragma unroll
    for (int r = 0; r < 4; ++r) {
      size_t off = (size_t)(i0 + r) * NMAT + j;
      sout[off] = oma * Ht[off] + alpha * q[off] * sa[r];
    }
  }
}

extern "C" void kernel_launch(void* const* d_in, const int* in_sizes, int n_in,
                              void* d_out, int out_size, void* d_ws,
                              size_t ws_size, hipStream_t stream) {
  const float* A1 = (const float*)d_in[0];
  const float* A2 = (const float*)d_in[1];
  const float* N1 = (const float*)d_in[2];
  const float* N2 = (const float*)d_in[3];
  const float* H = (const float*)d_in[4];
  float* s_out = (float*)d_out;

  char* p = (char*)d_ws;
  auto take = [&](size_t bytes) {
    char* r = p;
    p += (bytes + 255) & ~(size_t)255;
    return r;
  };
  unsigned short* idx1 = (unsigned short*)take((size_t)NMAT * CAP * 2);
  unsigned short* idx2 = (unsigned short*)take((size_t)NMAT * CAP * 2);
  unsigned short* idx2T = (unsigned short*)take((size_t)CAP * NMAT * 2);
  int* cnt1 = (int*)take((size_t)NMAT * 4);
  int* cnt2 = (int*)take((size_t)NMAT * 4);
  float* N1n = (float*)take((size_t)NMAT * KATTR * 4);
  float* N2n = (float*)take((size_t)NMAT * KATTR * 4);
  float* C1 = (float*)take((size_t)NMAT * KATTR * 4);
  float* C2 = (float*)take((size_t)NMAT * KATTR * 4);
  float* Ht = (float*)take((size_t)NMAT * NMAT * 4);
  float* q = (float*)take((size_t)NMAT * NMAT * 4);
  float* Q2 = (float*)take((size_t)NMAT * NMAT * 4);
  unsigned short* Mb0 = (unsigned short*)take((size_t)NMAT * NMAT * 2);
  unsigned short* Mb1 = (unsigned short*)take((size_t)NMAT * NMAT * 2);
  unsigned short* M0b = (unsigned short*)take((size_t)NMAT * NMAT * 2);
  float* Mf = (float*)take((size_t)NMAT * NMAT * 4);
  float* T1 = (float*)take((size_t)NMAT * NMAT * 4);
  if ((size_t)(p - (char*)d_ws) > ws_size) return;

  k_build<<<NMAT, 256, 0, stream>>>(A1, idx1, (unsigned short*)nullptr, cnt1);
  k_build<<<NMAT, 256, 0, stream>>>(A2, idx2, idx2T, cnt2);
  k_norm<<<NMAT / 4, 256, 0, stream>>>(N1, N1n);
  k_norm<<<NMAT / 4, 256, 0, stream>>>(N2, N2n);
  k_gatherN<<<NMAT, 64, 0, stream>>>(idx1, cnt1, N1n, C1);
  k_gatherN<<<NMAT, 64, 0, stream>>>(idx2, cnt2, N2n, C2);
  k_transpose<<<dim3(32, 32), 256, 0, stream>>>(H, Ht);
  k_q<<<dim3(32, 32), 256, 0, stream>>>(N1n, C1, N2n, C2, Ht, q, Q2, Mb0,
                                        M0b);
  for (int it = 0; it < NITER - 1; ++it) {
    const unsigned short* Min = (it & 1) ? Mb1 : Mb0;
    unsigned short* Mout = (it & 1) ? Mb0 : Mb1;
    int out32 = (it == NITER - 2) ? 1 : 0;
    k1s<<<4 * NSTRIPE, 1024, 0, stream>>>(idx1, cnt1, Min, T1);
    k2s<<<NMAT / 4, 1024, 0, stream>>>(idx2T, cnt2, T1, Q2, M0b, Mout, Mf,
                                       out32);
  }
  k_iter<<<NMAT / 4, 1024, 0, stream>>>(idx1, cnt1, idx2T, cnt2, Mf, q, Ht,
                                        s_out);
}